// Round 4
// baseline (19204.030 us; speedup 1.0000x reference)
//
#include <hip/hip_runtime.h>

#define T_ 256
#define B_ 64
#define H_ 1024
#define H3_ 3072
#define TB_ (T_*B_)

typedef unsigned short u16;
typedef unsigned int u32;
typedef __attribute__((ext_vector_type(8))) __bf16 bf16x8;
typedef __attribute__((ext_vector_type(4))) float f32x4;

#define AS1 __attribute__((address_space(1)))
#define AS3 __attribute__((address_space(3)))

__device__ __forceinline__ float bf2f(u16 u) {
    return __builtin_bit_cast(float, (u32)u << 16);
}
__device__ __forceinline__ u16 f2bf(float f) {
    u32 t = __builtin_bit_cast(u32, f);
    t += 0x7FFFu + ((t >> 16) & 1u);   // round-to-nearest-even
    return (u16)(t >> 16);
}
__device__ __forceinline__ f32x4 mfma16(bf16x8 a, bf16x8 b, f32x4 c) {
    return __builtin_amdgcn_mfma_f32_16x16x32_bf16(a, b, c, 0, 0, 0);
}
__device__ __forceinline__ float sigm(float x) { return 1.f / (1.f + __expf(-x)); }
__device__ __forceinline__ float tanh_(float x) { return 1.f - 2.f / (__expf(2.f * x) + 1.f); }

// ---------------------------------------------------------------- dtype detect
__global__ void k_detect(const u32* __restrict__ embw, u32* __restrict__ flag) {
    __shared__ int cnt[256];
    const int tid = threadIdx.x;
    int c = 0;
#pragma unroll
    for (int i = 0; i < 16; i++) {
        u32 w = embw[tid * 16 + i];
        int e = (w >> 7) & 0xFF;
        c += (e >= 117 && e <= 130) ? 1 : 0;
    }
    cnt[tid] = c;
    __syncthreads();
    for (int s = 128; s > 0; s >>= 1) {
        if (tid < s) cnt[tid] += cnt[tid + s];
        __syncthreads();
    }
    if (tid == 0) flag[0] = (cnt[0] < 2048) ? 1u : 0u;
}

// ---------------------------------------------------------------- weight conversion
struct CvtTable {
    const void* s[14];
    int off[14];
    int n[14];
};

__global__ void k_cvt(CvtTable tab, const u32* __restrict__ flag, u16* __restrict__ dst) {
    const bool f32 = flag[0] != 0;
    const int gtid = blockIdx.x * 256 + threadIdx.x;
    const int gstride = gridDim.x * 256;
    for (int ti = 0; ti < 14; ti++) {
        const int n = tab.n[ti], n4 = n >> 2;
        u16* d = dst + tab.off[ti];
        if (f32) {
            const float4* s4 = (const float4*)tab.s[ti];
            for (int i = gtid; i < n4; i += gstride) {
                float4 v = s4[i];
                ((ushort4*)d)[i] = make_ushort4(f2bf(v.x), f2bf(v.y), f2bf(v.z), f2bf(v.w));
            }
            const float* s1 = (const float*)tab.s[ti];
            for (int i = (n4 << 2) + gtid; i < n; i += gstride) d[i] = f2bf(s1[i]);
        } else {
            const ushort4* s4 = (const ushort4*)tab.s[ti];
            for (int i = gtid; i < n4; i += gstride) ((ushort4*)d)[i] = s4[i];
            const u16* s1 = (const u16*)tab.s[ti];
            for (int i = (n4 << 2) + gtid; i < n; i += gstride) d[i] = s1[i];
        }
    }
}

// ---------------------------------------------------------------- embedding + relu
__global__ void k_embed(const int* __restrict__ tok, const void* __restrict__ emb,
                        const u32* __restrict__ flag, u16* __restrict__ x) {
    int c = blockIdx.x * 256 + threadIdx.x;
    int row = c >> 7;
    int off = (c & 127) * 8;
    int t = tok[row]; t = t < 0 ? 0 : t;
    u32 a[4];
    if (flag[0]) {
        const float* e = (const float*)emb + (size_t)t * H_ + off;
        float4 v0 = *(const float4*)(e);
        float4 v1 = *(const float4*)(e + 4);
        float f[8] = {v0.x, v0.y, v0.z, v0.w, v1.x, v1.y, v1.z, v1.w};
#pragma unroll
        for (int i = 0; i < 4; i++) {
            float lo = f[2 * i] > 0.f ? f[2 * i] : 0.f;
            float hi = f[2 * i + 1] > 0.f ? f[2 * i + 1] : 0.f;
            a[i] = (u32)f2bf(lo) | ((u32)f2bf(hi) << 16);
        }
    } else {
        uint4 v = *(const uint4*)((const u16*)emb + (size_t)t * H_ + off);
        a[0] = v.x; a[1] = v.y; a[2] = v.z; a[3] = v.w;
#pragma unroll
        for (int i = 0; i < 4; i++) {
            u32 m = 0;
            if (!(a[i] & 0x8000u))     m |= 0x0000FFFFu;
            if (!(a[i] & 0x80000000u)) m |= 0xFFFF0000u;
            a[i] &= m;
        }
    }
    *(uint4*)(x + (size_t)c * 8) = make_uint4(a[0], a[1], a[2], a[3]);
}

// ---------------------------------------------------------------- Gi = A @ W^T + bias
// A [TB][1024] bf16 row-major; W [3072][1024]; C col-major per step: [T][3072][64]
__global__ __launch_bounds__(256) void k_gemm(const u16* __restrict__ A,
                                              const u16* __restrict__ W,
                                              const u16* __restrict__ bias,
                                              u16* __restrict__ C) {
    __shared__ u16 As[128 * 32];
    __shared__ u16 Bs[128 * 32];
    const int tid = threadIdx.x, w = tid >> 6, lane = tid & 63;
    const int n = lane & 15, q = lane >> 4;
    const int bn = blockIdx.x, bm = blockIdx.y;
    const size_t arow0 = (size_t)bm * 128;
    const int wc0 = bn * 128;
    const int wm = (w >> 1) * 64, wn = (w & 1) * 64;
    const int lr = lane >> 2, lc = (lane & 3) * 8;

    f32x4 acc[4][4];
#pragma unroll
    for (int i = 0; i < 4; i++)
#pragma unroll
        for (int j = 0; j < 4; j++) acc[i][j] = (f32x4){0.f, 0.f, 0.f, 0.f};

    for (int k0 = 0; k0 < H_; k0 += 32) {
        __syncthreads();
#pragma unroll
        for (int j2 = 0; j2 < 2; j2++) {
            const int j = w + j2 * 4;
            const u16* ga = A + (arow0 + j * 16 + lr) * H_ + k0 + lc;
            const u16* gb = W + ((size_t)(wc0 + j * 16 + lr)) * H_ + k0 + lc;
            __builtin_amdgcn_global_load_lds((const AS1 u32*)ga, (AS3 u32*)(As + j * 512), 16, 0, 0);
            __builtin_amdgcn_global_load_lds((const AS1 u32*)gb, (AS3 u32*)(Bs + j * 512), 16, 0, 0);
        }
        __builtin_amdgcn_s_waitcnt(0x0f70);   // vmcnt(0)
        __syncthreads();
        bf16x8 af[4], bfr[4];
#pragma unroll
        for (int mt = 0; mt < 4; mt++) af[mt] = *(const bf16x8*)(As + (wm + mt * 16 + n) * 32 + q * 8);
#pragma unroll
        for (int nt = 0; nt < 4; nt++) bfr[nt] = *(const bf16x8*)(Bs + (wn + nt * 16 + n) * 32 + q * 8);
#pragma unroll
        for (int mt = 0; mt < 4; mt++)
#pragma unroll
            for (int nt = 0; nt < 4; nt++) acc[mt][nt] = mfma16(af[mt], bfr[nt], acc[mt][nt]);
    }
#pragma unroll
    for (int nt = 0; nt < 4; nt++) {
        const int col = wc0 + wn + nt * 16 + n;
        const float bv = bf2f(bias[col]);
#pragma unroll
        for (int mt = 0; mt < 4; mt++) {
            const int rbase = wm + mt * 16 + q * 4;
            const int tt = (int)(arow0 >> 6) + (rbase >> 6);
            const int rmod = rbase & 63;
            ushort4 o;
            o.x = f2bf(acc[mt][nt][0] + bv);
            o.y = f2bf(acc[mt][nt][1] + bv);
            o.z = f2bf(acc[mt][nt][2] + bv);
            o.w = f2bf(acc[mt][nt][3] + bv);
            *(ushort4*)(C + ((size_t)tt * H3_ + col) * 64 + rmod) = o;
        }
    }
}

// ---------------------------------------------------------------- grid barrier
// Flag-array barrier: WG wg release-stores `epoch` into its own 128B line;
// wave 0 polls all 64 lines (one lane per line) until all >= epoch.
// No same-line RMW serialization (the R2/R3 barrier cost ~64 x ~175ns = ~11us/step).
__device__ __forceinline__ void gridbar(u32* bar, int epoch, int wg) {
    __syncthreads();
    const int tid = threadIdx.x;
    if (tid == 0) {
        __threadfence();   // release: make h/seq writes visible before arrival
        __hip_atomic_store(bar + wg * 32, (u32)epoch, __ATOMIC_RELEASE, __HIP_MEMORY_SCOPE_AGENT);
    }
    if (tid < 64) {
        while (__hip_atomic_load(bar + tid * 32, __ATOMIC_ACQUIRE, __HIP_MEMORY_SCOPE_AGENT) < (u32)epoch) {
            __builtin_amdgcn_s_sleep(2);
        }
    }
    __syncthreads();
    __threadfence();       // acquire: invalidate before reading peers' h
}

// ---------------------------------------------------------------- recurrent GRU layer
struct RecGrp {
    const u16* Whh; const u16* bhh; const u16* Gi; const u16* h0;
    u16* seq; u16* hbuf; u16* hfin;
    int relu_out; int sep_h;
    u32* bar;
};

__global__ __launch_bounds__(256, 1) void k_rec(RecGrp Ga, RecGrp Gb) {
    const RecGrp G = (blockIdx.x < 64) ? Ga : Gb;
    const int wg = blockIdx.x & 63, c0 = wg * 16;
    const int tid = threadIdx.x, w = tid >> 6, lane = tid & 63;
    const int n = lane & 15, q = lane >> 4;
    const int kb = w * 256;
    const int row0 = w * 16 + q * 4;
    __shared__ f32x4 part[4][4][3][64];     // 48KB

    bf16x8 bw[3][8];
#pragma unroll
    for (int g = 0; g < 3; g++)
#pragma unroll
        for (int kk = 0; kk < 8; kk++)
            bw[g][kk] = *(const bf16x8*)(G.Whh + (size_t)(g * H_ + c0 + n) * H_ + kb + kk * 32 + q * 8);

    float bh[3];
#pragma unroll
    for (int g = 0; g < 3; g++) bh[g] = bf2f(G.bhh[g * H_ + c0 + n]);

    float hr[4];
#pragma unroll
    for (int e = 0; e < 4; e++) hr[e] = G.h0 ? bf2f(G.h0[(size_t)(row0 + e) * H_ + c0 + n]) : 0.f;

    ushort4 gc[3], gn[3];
#pragma unroll
    for (int g = 0; g < 3; g++)
        gc[g] = *(const ushort4*)(G.Gi + ((size_t)0 * H3_ + g * H_ + c0 + n) * 64 + row0);

    int epoch = 1;
    for (int t = 0; t < T_; t++) {
        const u16* hsrc = (t == 0) ? G.h0
                          : (G.sep_h ? (const u16*)(G.hbuf + (size_t)(t & 1) * B_ * H_)
                                     : (const u16*)(G.seq + (size_t)(t - 1) * B_ * H_));
        if (t + 1 < T_) {
#pragma unroll
            for (int g = 0; g < 3; g++)
                gn[g] = *(const ushort4*)(G.Gi + ((size_t)(t + 1) * H3_ + g * H_ + c0 + n) * 64 + row0);
        }

        f32x4 gv[3];
        if (hsrc) {
            f32x4 acc[4][3];
#pragma unroll
            for (int m = 0; m < 4; m++)
#pragma unroll
                for (int g = 0; g < 3; g++) acc[m][g] = (f32x4){0.f, 0.f, 0.f, 0.f};
#pragma unroll
            for (int kk = 0; kk < 8; kk++) {
                bf16x8 a[4];
#pragma unroll
                for (int m = 0; m < 4; m++)
                    a[m] = *(const bf16x8*)(hsrc + (size_t)(m * 16 + n) * H_ + kb + kk * 32 + q * 8);
#pragma unroll
                for (int m = 0; m < 4; m++)
#pragma unroll
                    for (int g = 0; g < 3; g++) acc[m][g] = mfma16(a[m], bw[g][kk], acc[m][g]);
            }
#pragma unroll
            for (int m = 0; m < 4; m++)
#pragma unroll
                for (int g = 0; g < 3; g++) part[w][m][g][lane] = acc[m][g];
            __syncthreads();
#pragma unroll
            for (int g = 0; g < 3; g++) {
                f32x4 s = part[0][w][g][lane];
#pragma unroll
                for (int sw = 1; sw < 4; sw++) s += part[sw][w][g][lane];
                gv[g] = s;
            }
        } else {
#pragma unroll
            for (int g = 0; g < 3; g++) gv[g] = (f32x4){0.f, 0.f, 0.f, 0.f};
        }

        u16* sp = G.seq + (size_t)t * B_ * H_ + c0 + n;
#pragma unroll
        for (int e = 0; e < 4; e++) {
            float gi_r = bf2f(((const u16*)&gc[0])[e]);
            float gi_z = bf2f(((const u16*)&gc[1])[e]);
            float gi_n = bf2f(((const u16*)&gc[2])[e]);
            float r = sigm(gi_r + gv[0][e] + bh[0]);
            float z = sigm(gi_z + gv[1][e] + bh[1]);
            float nn = tanh_(gi_n + r * (gv[2][e] + bh[2]));
            hr[e] = (1.f - z) * nn + z * hr[e];
            u16 hb16 = f2bf(hr[e]);
            u16 ov = hb16;
            if (G.relu_out && (ov & 0x8000u)) ov = 0;
            sp[(size_t)(row0 + e) * H_] = ov;
            if (G.sep_h)
                G.hbuf[((size_t)((t + 1) & 1) * B_ + row0 + e) * H_ + c0 + n] = hb16;
        }
        if (t == T_ - 1 && G.hfin) {
#pragma unroll
            for (int e = 0; e < 4; e++)
                G.hfin[(size_t)(row0 + e) * H_ + c0 + n] = f2bf(hr[e]);
        }
#pragma unroll
        for (int g = 0; g < 3; g++) gc[g] = gn[g];
        gridbar(G.bar, epoch++, wg);
    }
}

// ---------------------------------------------------------------- score
__global__ void k_score(const u16* __restrict__ seq0, const u16* __restrict__ seq1,
                        const u16* __restrict__ Wv, const u16* __restrict__ bp,
                        const u32* __restrict__ flag, void* __restrict__ out) {
    const int w = threadIdx.x >> 6, lane = threadIdx.x & 63;
    const size_t row = (size_t)blockIdx.x * 4 + w;
    float s = 0.f;
#pragma unroll
    for (int half = 0; half < 2; half++) {
        const u16* p = (half ? seq1 : seq0) + row * H_;
        const u16* wv = Wv + half * H_;
#pragma unroll
        for (int c = 0; c < 2; c++) {
            const int off = c * 512 + lane * 8;
            uint4 ua = *(const uint4*)(p + off);
            uint4 ub = *(const uint4*)(wv + off);
            const u32 va[4] = {ua.x, ua.y, ua.z, ua.w};
            const u32 vb[4] = {ub.x, ub.y, ub.z, ub.w};
#pragma unroll
            for (int i = 0; i < 4; i++) {
                s += bf2f((u16)(va[i] & 0xFFFFu)) * bf2f((u16)(vb[i] & 0xFFFFu));
                s += bf2f((u16)(va[i] >> 16)) * bf2f((u16)(vb[i] >> 16));
            }
        }
    }
#pragma unroll
    for (int d = 32; d > 0; d >>= 1) s += __shfl_down(s, d, 64);
    if (lane == 0) {
        float r = sigm(s + bf2f(bp[0]));
        if (flag[0]) ((float*)out)[row] = r;
        else         ((u16*)out)[row] = f2bf(r);
    }
}

// ---------------------------------------------------------------- launcher
extern "C" void kernel_launch(void* const* d_in, const int* in_sizes, int n_in,
                              void* d_out, int out_size, void* d_ws, size_t ws_size,
                              hipStream_t stream) {
    const int* tok = (const int*)d_in[0];

    char* ws = (char*)d_ws;
    size_t off = 0;
    auto alloc = [&](size_t b) { void* p = ws + off; off += (b + 255) & ~(size_t)255; return p; };
    u32* bar  = (u32*)alloc(6 * 8192);        // 6 groups x 64 lines x 128B
    u32* flag = (u32*)alloc(256);
    u16* bufA = (u16*)alloc((size_t)TB_ * H_ * 2);
    u16* bufB = (u16*)alloc((size_t)TB_ * H_ * 2);
    u16* Gi0  = (u16*)alloc((size_t)T_ * H3_ * 64 * 2);
    u16* hfin[4];
    for (int i = 0; i < 4; i++) hfin[i] = (u16*)alloc((size_t)B_ * H_ * 2);
    u16* hbufE = (u16*)alloc((size_t)2 * B_ * H_ * 2);
    u16* wc = (u16*)alloc((size_t)37787656 * 2);
    u16* Gi1  = (u16*)alloc((size_t)T_ * H3_ * 64 * 2);
    const bool dualGi = (off <= ws_size);

    const int NW = 6291456;   // [L,3H,H]
    const int NB = 6144;      // [L,3H]
    int offs[14], szs[14];
    int cur = 0;
    for (int i = 0; i < 6; i++) { offs[i] = cur; szs[i] = NW; cur += NW; }
    for (int i = 6; i < 12; i++) { offs[i] = cur; szs[i] = NB; cur += NB; }
    offs[12] = cur; szs[12] = 2048; cur += 2048;
    offs[13] = cur; szs[13] = 1; cur += 8;

    CvtTable tab;
    const int big_idx[6]  = {2, 3, 6, 7, 10, 11};
    const int bias_idx[6] = {4, 5, 8, 9, 12, 13};
    for (int i = 0; i < 6; i++) { tab.s[i] = d_in[big_idx[i]]; tab.off[i] = offs[i]; tab.n[i] = szs[i]; }
    for (int i = 0; i < 6; i++) { tab.s[6 + i] = d_in[bias_idx[i]]; tab.off[6 + i] = offs[6 + i]; tab.n[6 + i] = szs[6 + i]; }
    tab.s[12] = d_in[14]; tab.off[12] = offs[12]; tab.n[12] = szs[12];
    tab.s[13] = d_in[15]; tab.off[13] = offs[13]; tab.n[13] = szs[13];

    const u16* eWih = wc + offs[0]; const u16* eWhh = wc + offs[1];
    const u16* gWih = wc + offs[2]; const u16* gWhh = wc + offs[3];
    const u16* cWih = wc + offs[4]; const u16* cWhh = wc + offs[5];
    const u16* ebih = wc + offs[6]; const u16* ebhh = wc + offs[7];
    const u16* gbih = wc + offs[8]; const u16* gbhh = wc + offs[9];
    const u16* cbih = wc + offs[10]; const u16* cbhh = wc + offs[11];
    const u16* sW = wc + offs[12]; const u16* sb = wc + offs[13];

    hipMemsetAsync(bar, 0, 6 * 8192, stream);
    k_detect<<<1, 256, 0, stream>>>((const u32*)d_in[1], flag);
    k_cvt<<<2048, 256, 0, stream>>>(tab, flag, wc);
    k_embed<<<8192, 256, 0, stream>>>(tok, d_in[1], flag, bufA);

    dim3 gg(24, 128);
    const size_t WL = (size_t)H3_ * H_;
    u32* barg[6];
    for (int i = 0; i < 6; i++) barg[i] = bar + i * 2048;

    RecGrp g;
    g.hbuf = nullptr; g.sep_h = 0; g.relu_out = 0;

    // encoder layer 0: bufA -> Gi0 -> seq bufB (seq doubles as h-chain)
    k_gemm<<<gg, 256, 0, stream>>>(bufA, eWih, ebih, Gi0);
    g.Whh = eWhh; g.bhh = ebhh; g.Gi = Gi0; g.h0 = nullptr;
    g.seq = bufB; g.hfin = hfin[0]; g.relu_out = 0; g.sep_h = 0; g.bar = barg[0];
    k_rec<<<64, 256, 0, stream>>>(g, g);
    // encoder layer 1: bufB -> Gi0 -> seq bufA (relu'd), raw h via hbufE
    k_gemm<<<gg, 256, 0, stream>>>(bufB, eWih + WL, ebih + H3_, Gi0);
    g.Whh = eWhh + WL; g.bhh = ebhh + H3_; g.Gi = Gi0; g.h0 = nullptr;
    g.seq = bufA; g.hbuf = hbufE; g.hfin = hfin[1]; g.relu_out = 1; g.sep_h = 1; g.bar = barg[1];
    k_rec<<<64, 256, 0, stream>>>(g, g);
    g.hbuf = nullptr; g.sep_h = 0; g.relu_out = 0;
    // gru layer 0 (h0 = enc0 final): bufA -> bufB
    k_gemm<<<gg, 256, 0, stream>>>(bufA, gWih, gbih, Gi0);
    g.Whh = gWhh; g.bhh = gbhh; g.Gi = Gi0; g.h0 = hfin[0];
    g.seq = bufB; g.hfin = hfin[2]; g.bar = barg[2];
    k_rec<<<64, 256, 0, stream>>>(g, g);
    // gru layer 1 (h0 = enc1 final): bufB -> bufA (gru_out)
    k_gemm<<<gg, 256, 0, stream>>>(bufB, gWih + WL, gbih + H3_, Gi0);
    g.Whh = gWhh + WL; g.bhh = gbhh + H3_; g.Gi = Gi0; g.h0 = hfin[1];
    g.seq = bufA; g.hfin = hfin[3]; g.bar = barg[3];
    k_rec<<<64, 256, 0, stream>>>(g, g);

    if (dualGi) {
        k_gemm<<<gg, 256, 0, stream>>>(bufA, cWih, cbih, Gi0);
        k_gemm<<<gg, 256, 0, stream>>>(bufA, cWih + WL, cbih + H3_, Gi1);
        RecGrp c0, c1;
        c0.Whh = cWhh; c0.bhh = cbhh; c0.Gi = Gi0; c0.h0 = hfin[2];
        c0.seq = bufB; c0.hbuf = nullptr; c0.hfin = nullptr; c0.relu_out = 0; c0.sep_h = 0; c0.bar = barg[4];
        c1.Whh = cWhh + WL; c1.bhh = cbhh + H3_; c1.Gi = Gi1; c1.h0 = hfin[3];
        c1.seq = bufA; c1.hbuf = nullptr; c1.hfin = nullptr; c1.relu_out = 0; c1.sep_h = 0; c1.bar = barg[5];
        k_rec<<<128, 256, 0, stream>>>(c0, c1);
    } else {
        k_gemm<<<gg, 256, 0, stream>>>(bufA, cWih, cbih, Gi0);
        g.Whh = cWhh; g.bhh = cbhh; g.Gi = Gi0; g.h0 = hfin[2];
        g.seq = bufB; g.hfin = nullptr; g.bar = barg[4];
        k_rec<<<64, 256, 0, stream>>>(g, g);
        k_gemm<<<gg, 256, 0, stream>>>(bufA, cWih + WL, cbih + H3_, Gi0);
        g.Whh = cWhh + WL; g.bhh = cbhh + H3_; g.Gi = Gi0; g.h0 = hfin[3];
        g.seq = bufA; g.hfin = nullptr; g.bar = barg[5];
        k_rec<<<64, 256, 0, stream>>>(g, g);
    }

    k_score<<<4096, 256, 0, stream>>>(bufB, bufA, sW, sb, flag, d_out);
}

// Round 5
// 13817.014 us; speedup vs baseline: 1.3899x; 1.3899x over previous
//
#include <hip/hip_runtime.h>

#define T_ 256
#define B_ 64
#define H_ 1024
#define H3_ 3072
#define TB_ (T_*B_)

typedef unsigned short u16;
typedef unsigned int u32;
typedef __attribute__((ext_vector_type(8))) __bf16 bf16x8;
typedef __attribute__((ext_vector_type(4))) float f32x4;

#define AS1 __attribute__((address_space(1)))
#define AS3 __attribute__((address_space(3)))

__device__ __forceinline__ float bf2f(u16 u) {
    return __builtin_bit_cast(float, (u32)u << 16);
}
__device__ __forceinline__ u16 f2bf(float f) {
    u32 t = __builtin_bit_cast(u32, f);
    t += 0x7FFFu + ((t >> 16) & 1u);   // round-to-nearest-even
    return (u16)(t >> 16);
}
__device__ __forceinline__ f32x4 mfma16(bf16x8 a, bf16x8 b, f32x4 c) {
    return __builtin_amdgcn_mfma_f32_16x16x32_bf16(a, b, c, 0, 0, 0);
}
__device__ __forceinline__ float sigm(float x) { return 1.f / (1.f + __expf(-x)); }
__device__ __forceinline__ float tanh_(float x) { return 1.f - 2.f / (__expf(2.f * x) + 1.f); }

// ---------------------------------------------------------------- dtype detect
__global__ void k_detect(const u32* __restrict__ embw, u32* __restrict__ flag) {
    __shared__ int cnt[256];
    const int tid = threadIdx.x;
    int c = 0;
#pragma unroll
    for (int i = 0; i < 16; i++) {
        u32 w = embw[tid * 16 + i];
        int e = (w >> 7) & 0xFF;
        c += (e >= 117 && e <= 130) ? 1 : 0;
    }
    cnt[tid] = c;
    __syncthreads();
    for (int s = 128; s > 0; s >>= 1) {
        if (tid < s) cnt[tid] += cnt[tid + s];
        __syncthreads();
    }
    if (tid == 0) flag[0] = (cnt[0] < 2048) ? 1u : 0u;
}

// ---------------------------------------------------------------- weight conversion
struct CvtTable {
    const void* s[14];
    int off[14];
    int n[14];
};

__global__ void k_cvt(CvtTable tab, const u32* __restrict__ flag, u16* __restrict__ dst) {
    const bool f32 = flag[0] != 0;
    const int gtid = blockIdx.x * 256 + threadIdx.x;
    const int gstride = gridDim.x * 256;
    for (int ti = 0; ti < 14; ti++) {
        const int n = tab.n[ti], n4 = n >> 2;
        u16* d = dst + tab.off[ti];
        if (f32) {
            const float4* s4 = (const float4*)tab.s[ti];
            for (int i = gtid; i < n4; i += gstride) {
                float4 v = s4[i];
                ((ushort4*)d)[i] = make_ushort4(f2bf(v.x), f2bf(v.y), f2bf(v.z), f2bf(v.w));
            }
            const float* s1 = (const float*)tab.s[ti];
            for (int i = (n4 << 2) + gtid; i < n; i += gstride) d[i] = f2bf(s1[i]);
        } else {
            const ushort4* s4 = (const ushort4*)tab.s[ti];
            for (int i = gtid; i < n4; i += gstride) ((ushort4*)d)[i] = s4[i];
            const u16* s1 = (const u16*)tab.s[ti];
            for (int i = (n4 << 2) + gtid; i < n; i += gstride) d[i] = s1[i];
        }
    }
}

// ---------------------------------------------------------------- embedding + relu
__global__ void k_embed(const int* __restrict__ tok, const void* __restrict__ emb,
                        const u32* __restrict__ flag, u16* __restrict__ x) {
    int c = blockIdx.x * 256 + threadIdx.x;
    int row = c >> 7;
    int off = (c & 127) * 8;
    int t = tok[row]; t = t < 0 ? 0 : t;
    u32 a[4];
    if (flag[0]) {
        const float* e = (const float*)emb + (size_t)t * H_ + off;
        float4 v0 = *(const float4*)(e);
        float4 v1 = *(const float4*)(e + 4);
        float f[8] = {v0.x, v0.y, v0.z, v0.w, v1.x, v1.y, v1.z, v1.w};
#pragma unroll
        for (int i = 0; i < 4; i++) {
            float lo = f[2 * i] > 0.f ? f[2 * i] : 0.f;
            float hi = f[2 * i + 1] > 0.f ? f[2 * i + 1] : 0.f;
            a[i] = (u32)f2bf(lo) | ((u32)f2bf(hi) << 16);
        }
    } else {
        uint4 v = *(const uint4*)((const u16*)emb + (size_t)t * H_ + off);
        a[0] = v.x; a[1] = v.y; a[2] = v.z; a[3] = v.w;
#pragma unroll
        for (int i = 0; i < 4; i++) {
            u32 m = 0;
            if (!(a[i] & 0x8000u))     m |= 0x0000FFFFu;
            if (!(a[i] & 0x80000000u)) m |= 0xFFFF0000u;
            a[i] &= m;
        }
    }
    *(uint4*)(x + (size_t)c * 8) = make_uint4(a[0], a[1], a[2], a[3]);
}

// ---------------------------------------------------------------- Gi = A @ W^T + bias
// A [TB][1024] bf16 row-major; W [3072][1024]; C col-major per step: [T][3072][64]
__global__ __launch_bounds__(256) void k_gemm(const u16* __restrict__ A,
                                              const u16* __restrict__ W,
                                              const u16* __restrict__ bias,
                                              u16* __restrict__ C) {
    __shared__ u16 As[128 * 32];
    __shared__ u16 Bs[128 * 32];
    const int tid = threadIdx.x, w = tid >> 6, lane = tid & 63;
    const int n = lane & 15, q = lane >> 4;
    const int bn = blockIdx.x, bm = blockIdx.y;
    const size_t arow0 = (size_t)bm * 128;
    const int wc0 = bn * 128;
    const int wm = (w >> 1) * 64, wn = (w & 1) * 64;
    const int lr = lane >> 2, lc = (lane & 3) * 8;

    f32x4 acc[4][4];
#pragma unroll
    for (int i = 0; i < 4; i++)
#pragma unroll
        for (int j = 0; j < 4; j++) acc[i][j] = (f32x4){0.f, 0.f, 0.f, 0.f};

    for (int k0 = 0; k0 < H_; k0 += 32) {
        __syncthreads();
#pragma unroll
        for (int j2 = 0; j2 < 2; j2++) {
            const int j = w + j2 * 4;
            const u16* ga = A + (arow0 + j * 16 + lr) * H_ + k0 + lc;
            const u16* gb = W + ((size_t)(wc0 + j * 16 + lr)) * H_ + k0 + lc;
            __builtin_amdgcn_global_load_lds((const AS1 u32*)ga, (AS3 u32*)(As + j * 512), 16, 0, 0);
            __builtin_amdgcn_global_load_lds((const AS1 u32*)gb, (AS3 u32*)(Bs + j * 512), 16, 0, 0);
        }
        __builtin_amdgcn_s_waitcnt(0x0f70);   // vmcnt(0)
        __syncthreads();
        bf16x8 af[4], bfr[4];
#pragma unroll
        for (int mt = 0; mt < 4; mt++) af[mt] = *(const bf16x8*)(As + (wm + mt * 16 + n) * 32 + q * 8);
#pragma unroll
        for (int nt = 0; nt < 4; nt++) bfr[nt] = *(const bf16x8*)(Bs + (wn + nt * 16 + n) * 32 + q * 8);
#pragma unroll
        for (int mt = 0; mt < 4; mt++)
#pragma unroll
            for (int nt = 0; nt < 4; nt++) acc[mt][nt] = mfma16(af[mt], bfr[nt], acc[mt][nt]);
    }
#pragma unroll
    for (int nt = 0; nt < 4; nt++) {
        const int col = wc0 + wn + nt * 16 + n;
        const float bv = bf2f(bias[col]);
#pragma unroll
        for (int mt = 0; mt < 4; mt++) {
            const int rbase = wm + mt * 16 + q * 4;
            const int tt = (int)(arow0 >> 6) + (rbase >> 6);
            const int rmod = rbase & 63;
            ushort4 o;
            o.x = f2bf(acc[mt][nt][0] + bv);
            o.y = f2bf(acc[mt][nt][1] + bv);
            o.z = f2bf(acc[mt][nt][2] + bv);
            o.w = f2bf(acc[mt][nt][3] + bv);
            *(ushort4*)(C + ((size_t)tt * H3_ + col) * 64 + rmod) = o;
        }
    }
}

// ---------------------------------------------------------------- grid barrier
// Flag-array barrier with RELAXED polls and exactly ONE release + ONE acquire
// fence per step. R2-R4 used ACQUIRE on every poll load (agent-scope acquire
// => buffer_inv, an XCD-wide L2 invalidate, per poll iteration) plus two
// __threadfence() (buffer_wbl2 L2 writebacks) per step -- that cache-maintenance
// storm was the ~13us/step floor, invariant across arrival mechanisms.
__device__ __forceinline__ void gridbar(u32* bar, int epoch, int wg) {
    __syncthreads();                      // all waves' h/seq stores drained to L2
    const int tid = threadIdx.x;
    if (tid == 0) {
        __builtin_amdgcn_fence(__ATOMIC_RELEASE, "agent");   // single wbl2: publish to L3
        __hip_atomic_store(bar + wg * 32, (u32)epoch, __ATOMIC_RELAXED, __HIP_MEMORY_SCOPE_AGENT);
    }
    if (tid < 64) {
        while (__hip_atomic_load(bar + tid * 32, __ATOMIC_RELAXED, __HIP_MEMORY_SCOPE_AGENT) < (u32)epoch) {
            __builtin_amdgcn_s_sleep(1);
        }
    }
    __syncthreads();
    __builtin_amdgcn_fence(__ATOMIC_ACQUIRE, "agent");       // single inv: see peers' h
}

// ---------------------------------------------------------------- recurrent GRU layer
struct RecGrp {
    const u16* Whh; const u16* bhh; const u16* Gi; const u16* h0;
    u16* seq; u16* hbuf; u16* hfin;
    int relu_out; int sep_h;
    u32* bar;
};

__global__ __launch_bounds__(256, 1) void k_rec(RecGrp Ga, RecGrp Gb) {
    const RecGrp G = (blockIdx.x < 64) ? Ga : Gb;
    const int wg = blockIdx.x & 63, c0 = wg * 16;
    const int tid = threadIdx.x, w = tid >> 6, lane = tid & 63;
    const int n = lane & 15, q = lane >> 4;
    const int kb = w * 256;
    const int row0 = w * 16 + q * 4;
    __shared__ f32x4 part[4][4][3][64];     // 48KB

    bf16x8 bw[3][8];
#pragma unroll
    for (int g = 0; g < 3; g++)
#pragma unroll
        for (int kk = 0; kk < 8; kk++)
            bw[g][kk] = *(const bf16x8*)(G.Whh + (size_t)(g * H_ + c0 + n) * H_ + kb + kk * 32 + q * 8);

    float bh[3];
#pragma unroll
    for (int g = 0; g < 3; g++) bh[g] = bf2f(G.bhh[g * H_ + c0 + n]);

    float hr[4];
#pragma unroll
    for (int e = 0; e < 4; e++) hr[e] = G.h0 ? bf2f(G.h0[(size_t)(row0 + e) * H_ + c0 + n]) : 0.f;

    ushort4 gc[3], gn[3];
#pragma unroll
    for (int g = 0; g < 3; g++)
        gc[g] = *(const ushort4*)(G.Gi + ((size_t)0 * H3_ + g * H_ + c0 + n) * 64 + row0);

    int epoch = 1;
    for (int t = 0; t < T_; t++) {
        const u16* hsrc = (t == 0) ? G.h0
                          : (G.sep_h ? (const u16*)(G.hbuf + (size_t)(t & 1) * B_ * H_)
                                     : (const u16*)(G.seq + (size_t)(t - 1) * B_ * H_));
        if (t + 1 < T_) {
#pragma unroll
            for (int g = 0; g < 3; g++)
                gn[g] = *(const ushort4*)(G.Gi + ((size_t)(t + 1) * H3_ + g * H_ + c0 + n) * 64 + row0);
        }

        f32x4 gv[3];
        if (hsrc) {
            f32x4 acc[4][3];
#pragma unroll
            for (int m = 0; m < 4; m++)
#pragma unroll
                for (int g = 0; g < 3; g++) acc[m][g] = (f32x4){0.f, 0.f, 0.f, 0.f};
#pragma unroll
            for (int kk = 0; kk < 8; kk++) {
                bf16x8 a[4];
#pragma unroll
                for (int m = 0; m < 4; m++)
                    a[m] = *(const bf16x8*)(hsrc + (size_t)(m * 16 + n) * H_ + kb + kk * 32 + q * 8);
#pragma unroll
                for (int m = 0; m < 4; m++)
#pragma unroll
                    for (int g = 0; g < 3; g++) acc[m][g] = mfma16(a[m], bw[g][kk], acc[m][g]);
            }
#pragma unroll
            for (int m = 0; m < 4; m++)
#pragma unroll
                for (int g = 0; g < 3; g++) part[w][m][g][lane] = acc[m][g];
            __syncthreads();
#pragma unroll
            for (int g = 0; g < 3; g++) {
                f32x4 s = part[0][w][g][lane];
#pragma unroll
                for (int sw = 1; sw < 4; sw++) s += part[sw][w][g][lane];
                gv[g] = s;
            }
        } else {
#pragma unroll
            for (int g = 0; g < 3; g++) gv[g] = (f32x4){0.f, 0.f, 0.f, 0.f};
        }

        u16* sp = G.seq + (size_t)t * B_ * H_ + c0 + n;
#pragma unroll
        for (int e = 0; e < 4; e++) {
            float gi_r = bf2f(((const u16*)&gc[0])[e]);
            float gi_z = bf2f(((const u16*)&gc[1])[e]);
            float gi_n = bf2f(((const u16*)&gc[2])[e]);
            float r = sigm(gi_r + gv[0][e] + bh[0]);
            float z = sigm(gi_z + gv[1][e] + bh[1]);
            float nn = tanh_(gi_n + r * (gv[2][e] + bh[2]));
            hr[e] = (1.f - z) * nn + z * hr[e];
            u16 hb16 = f2bf(hr[e]);
            u16 ov = hb16;
            if (G.relu_out && (ov & 0x8000u)) ov = 0;
            sp[(size_t)(row0 + e) * H_] = ov;
            if (G.sep_h)
                G.hbuf[((size_t)((t + 1) & 1) * B_ + row0 + e) * H_ + c0 + n] = hb16;
        }
        if (t == T_ - 1 && G.hfin) {
#pragma unroll
            for (int e = 0; e < 4; e++)
                G.hfin[(size_t)(row0 + e) * H_ + c0 + n] = f2bf(hr[e]);
        }
#pragma unroll
        for (int g = 0; g < 3; g++) gc[g] = gn[g];
        gridbar(G.bar, epoch++, wg);
    }
}

// ---------------------------------------------------------------- score
__global__ void k_score(const u16* __restrict__ seq0, const u16* __restrict__ seq1,
                        const u16* __restrict__ Wv, const u16* __restrict__ bp,
                        const u32* __restrict__ flag, void* __restrict__ out) {
    const int w = threadIdx.x >> 6, lane = threadIdx.x & 63;
    const size_t row = (size_t)blockIdx.x * 4 + w;
    float s = 0.f;
#pragma unroll
    for (int half = 0; half < 2; half++) {
        const u16* p = (half ? seq1 : seq0) + row * H_;
        const u16* wv = Wv + half * H_;
#pragma unroll
        for (int c = 0; c < 2; c++) {
            const int off = c * 512 + lane * 8;
            uint4 ua = *(const uint4*)(p + off);
            uint4 ub = *(const uint4*)(wv + off);
            const u32 va[4] = {ua.x, ua.y, ua.z, ua.w};
            const u32 vb[4] = {ub.x, ub.y, ub.z, ub.w};
#pragma unroll
            for (int i = 0; i < 4; i++) {
                s += bf2f((u16)(va[i] & 0xFFFFu)) * bf2f((u16)(vb[i] & 0xFFFFu));
                s += bf2f((u16)(va[i] >> 16)) * bf2f((u16)(vb[i] >> 16));
            }
        }
    }
#pragma unroll
    for (int d = 32; d > 0; d >>= 1) s += __shfl_down(s, d, 64);
    if (lane == 0) {
        float r = sigm(s + bf2f(bp[0]));
        if (flag[0]) ((float*)out)[row] = r;
        else         ((u16*)out)[row] = f2bf(r);
    }
}

// ---------------------------------------------------------------- launcher
extern "C" void kernel_launch(void* const* d_in, const int* in_sizes, int n_in,
                              void* d_out, int out_size, void* d_ws, size_t ws_size,
                              hipStream_t stream) {
    const int* tok = (const int*)d_in[0];

    char* ws = (char*)d_ws;
    size_t off = 0;
    auto alloc = [&](size_t b) { void* p = ws + off; off += (b + 255) & ~(size_t)255; return p; };
    u32* bar  = (u32*)alloc(6 * 8192);        // 6 groups x 64 lines x 128B
    u32* flag = (u32*)alloc(256);
    u16* bufA = (u16*)alloc((size_t)TB_ * H_ * 2);
    u16* bufB = (u16*)alloc((size_t)TB_ * H_ * 2);
    u16* Gi0  = (u16*)alloc((size_t)T_ * H3_ * 64 * 2);
    u16* hfin[4];
    for (int i = 0; i < 4; i++) hfin[i] = (u16*)alloc((size_t)B_ * H_ * 2);
    u16* hbufE = (u16*)alloc((size_t)2 * B_ * H_ * 2);
    u16* wc = (u16*)alloc((size_t)37787656 * 2);
    u16* Gi1  = (u16*)alloc((size_t)T_ * H3_ * 64 * 2);
    const bool dualGi = (off <= ws_size);

    const int NW = 6291456;   // [L,3H,H]
    const int NB = 6144;      // [L,3H]
    int offs[14], szs[14];
    int cur = 0;
    for (int i = 0; i < 6; i++) { offs[i] = cur; szs[i] = NW; cur += NW; }
    for (int i = 6; i < 12; i++) { offs[i] = cur; szs[i] = NB; cur += NB; }
    offs[12] = cur; szs[12] = 2048; cur += 2048;
    offs[13] = cur; szs[13] = 1; cur += 8;

    CvtTable tab;
    const int big_idx[6]  = {2, 3, 6, 7, 10, 11};
    const int bias_idx[6] = {4, 5, 8, 9, 12, 13};
    for (int i = 0; i < 6; i++) { tab.s[i] = d_in[big_idx[i]]; tab.off[i] = offs[i]; tab.n[i] = szs[i]; }
    for (int i = 0; i < 6; i++) { tab.s[6 + i] = d_in[bias_idx[i]]; tab.off[6 + i] = offs[6 + i]; tab.n[6 + i] = szs[6 + i]; }
    tab.s[12] = d_in[14]; tab.off[12] = offs[12]; tab.n[12] = szs[12];
    tab.s[13] = d_in[15]; tab.off[13] = offs[13]; tab.n[13] = szs[13];

    const u16* eWih = wc + offs[0]; const u16* eWhh = wc + offs[1];
    const u16* gWih = wc + offs[2]; const u16* gWhh = wc + offs[3];
    const u16* cWih = wc + offs[4]; const u16* cWhh = wc + offs[5];
    const u16* ebih = wc + offs[6]; const u16* ebhh = wc + offs[7];
    const u16* gbih = wc + offs[8]; const u16* gbhh = wc + offs[9];
    const u16* cbih = wc + offs[10]; const u16* cbhh = wc + offs[11];
    const u16* sW = wc + offs[12]; const u16* sb = wc + offs[13];

    hipMemsetAsync(bar, 0, 6 * 8192, stream);
    k_detect<<<1, 256, 0, stream>>>((const u32*)d_in[1], flag);
    k_cvt<<<2048, 256, 0, stream>>>(tab, flag, wc);
    k_embed<<<8192, 256, 0, stream>>>(tok, d_in[1], flag, bufA);

    dim3 gg(24, 128);
    const size_t WL = (size_t)H3_ * H_;
    u32* barg[6];
    for (int i = 0; i < 6; i++) barg[i] = bar + i * 2048;

    RecGrp g;
    g.hbuf = nullptr; g.sep_h = 0; g.relu_out = 0;

    // encoder layer 0: bufA -> Gi0 -> seq bufB (seq doubles as h-chain)
    k_gemm<<<gg, 256, 0, stream>>>(bufA, eWih, ebih, Gi0);
    g.Whh = eWhh; g.bhh = ebhh; g.Gi = Gi0; g.h0 = nullptr;
    g.seq = bufB; g.hfin = hfin[0]; g.relu_out = 0; g.sep_h = 0; g.bar = barg[0];
    k_rec<<<64, 256, 0, stream>>>(g, g);
    // encoder layer 1: bufB -> Gi0 -> seq bufA (relu'd), raw h via hbufE
    k_gemm<<<gg, 256, 0, stream>>>(bufB, eWih + WL, ebih + H3_, Gi0);
    g.Whh = eWhh + WL; g.bhh = ebhh + H3_; g.Gi = Gi0; g.h0 = nullptr;
    g.seq = bufA; g.hbuf = hbufE; g.hfin = hfin[1]; g.relu_out = 1; g.sep_h = 1; g.bar = barg[1];
    k_rec<<<64, 256, 0, stream>>>(g, g);
    g.hbuf = nullptr; g.sep_h = 0; g.relu_out = 0;
    // gru layer 0 (h0 = enc0 final): bufA -> bufB
    k_gemm<<<gg, 256, 0, stream>>>(bufA, gWih, gbih, Gi0);
    g.Whh = gWhh; g.bhh = gbhh; g.Gi = Gi0; g.h0 = hfin[0];
    g.seq = bufB; g.hfin = hfin[2]; g.bar = barg[2];
    k_rec<<<64, 256, 0, stream>>>(g, g);
    // gru layer 1 (h0 = enc1 final): bufB -> bufA (gru_out)
    k_gemm<<<gg, 256, 0, stream>>>(bufB, gWih + WL, gbih + H3_, Gi0);
    g.Whh = gWhh + WL; g.bhh = gbhh + H3_; g.Gi = Gi0; g.h0 = hfin[1];
    g.seq = bufA; g.hfin = hfin[3]; g.bar = barg[3];
    k_rec<<<64, 256, 0, stream>>>(g, g);

    if (dualGi) {
        k_gemm<<<gg, 256, 0, stream>>>(bufA, cWih, cbih, Gi0);
        k_gemm<<<gg, 256, 0, stream>>>(bufA, cWih + WL, cbih + H3_, Gi1);
        RecGrp c0, c1;
        c0.Whh = cWhh; c0.bhh = cbhh; c0.Gi = Gi0; c0.h0 = hfin[2];
        c0.seq = bufB; c0.hbuf = nullptr; c0.hfin = nullptr; c0.relu_out = 0; c0.sep_h = 0; c0.bar = barg[4];
        c1.Whh = cWhh + WL; c1.bhh = cbhh + H3_; c1.Gi = Gi1; c1.h0 = hfin[3];
        c1.seq = bufA; c1.hbuf = nullptr; c1.hfin = nullptr; c1.relu_out = 0; c1.sep_h = 0; c1.bar = barg[5];
        k_rec<<<128, 256, 0, stream>>>(c0, c1);
    } else {
        k_gemm<<<gg, 256, 0, stream>>>(bufA, cWih, cbih, Gi0);
        g.Whh = cWhh; g.bhh = cbhh; g.Gi = Gi0; g.h0 = hfin[2];
        g.seq = bufB; g.hfin = nullptr; g.bar = barg[4];
        k_rec<<<64, 256, 0, stream>>>(g, g);
        k_gemm<<<gg, 256, 0, stream>>>(bufA, cWih + WL, cbih + H3_, Gi0);
        g.Whh = cWhh + WL; g.bhh = cbhh + H3_; g.Gi = Gi0; g.h0 = hfin[3];
        g.seq = bufA; g.hfin = nullptr; g.bar = barg[5];
        k_rec<<<64, 256, 0, stream>>>(g, g);
    }

    k_score<<<4096, 256, 0, stream>>>(bufB, bufA, sW, sb, flag, d_out);
}